// Round 12
// baseline (306.019 us; speedup 1.0000x reference)
//
#include <hip/hip_runtime.h>
#include <cstdint>
#include <cstddef>

#define D_MODEL 768
#define D_STATE 16
#define D_CONV  4
#define INNER   1536
#define BATCH   2
#define SEQLEN  2048
#define M_TOK   (BATCH * SEQLEN)   // 4096
#define NCH     (BATCH * INNER)    // 3072
#define NCHUNK  128
#define CL      (SEQLEN / NCHUNK)  // 16

typedef unsigned short u16;
typedef __attribute__((ext_vector_type(4))) unsigned short us4;
typedef __attribute__((ext_vector_type(8))) short bf8;
typedef __attribute__((ext_vector_type(4))) float f32x4;
typedef __attribute__((ext_vector_type(4))) int i32x4;

#define INV254 (1.f / 254.f)

__device__ __forceinline__ u16 f2bf(float f) {
    uint32_t x = __float_as_uint(f);
    return (u16)((x + 0x7fffu + ((x >> 16) & 1u)) >> 16);
}
__device__ __forceinline__ float bf2f(u16 h) {
    return __uint_as_float(((uint32_t)h) << 16);
}
__device__ __forceinline__ int pk8(float a, float b, float c, float d) {
    return ((int)a & 0xff) | (((int)b & 0xff) << 8) |
           (((int)c & 0xff) << 16) | (((int)d & 0xff) << 24);
}

// ---------------------------------------------------------------------------
// Fused preprocessing, one launch:
//  seg0: rowquant hs   (4096 rows, K=768)
//  seg1: rowquant in_w (3072 rows, K=768)
//  seg2: rowquant dt_w (1536 rows, K=1536)
//  seg3: bf16 hi/lo split of out_w (1152 blocks x 256 float4)
// rowquant: s = rowmax/127, A ~= s*(a1 + a0/254), one block per row.
// ---------------------------------------------------------------------------
__global__ __launch_bounds__(256) void prep_all(
    const float* __restrict__ hs, int8_t* __restrict__ hs1, int8_t* __restrict__ hs0, float* __restrict__ sc_hs,
    const float* __restrict__ iw, int8_t* __restrict__ iw1, int8_t* __restrict__ iw0, float* __restrict__ sc_iw,
    const float* __restrict__ dw, int8_t* __restrict__ dw1, int8_t* __restrict__ dw0, float* __restrict__ sc_dw,
    const float* __restrict__ ow, u16* __restrict__ owh, u16* __restrict__ owl)
{
    const int blk = blockIdx.x;
    const int tid = threadIdx.x;

    if (blk >= M_TOK + 2 * INNER + INNER) {          // seg3: cvt out_w
        const int j = (blk - (M_TOK + 3 * INNER)) * 256 + tid;
        const int n4 = D_MODEL * INNER / 4;
        if (j >= n4) return;
        const float4 v = ((const float4*)ow)[j];
        us4 h, l;
        h.x = f2bf(v.x); l.x = f2bf(v.x - bf2f(h.x));
        h.y = f2bf(v.y); l.y = f2bf(v.y - bf2f(h.y));
        h.z = f2bf(v.z); l.z = f2bf(v.z - bf2f(h.z));
        h.w = f2bf(v.w); l.w = f2bf(v.w - bf2f(h.w));
        ((us4*)owh)[j] = h;
        ((us4*)owl)[j] = l;
        return;
    }

    const float* src; int8_t* q1; int8_t* q0; float* sc; int K; int row;
    if (blk < M_TOK) {
        src = hs; q1 = hs1; q0 = hs0; sc = sc_hs; K = D_MODEL; row = blk;
    } else if (blk < M_TOK + 2 * INNER) {
        src = iw; q1 = iw1; q0 = iw0; sc = sc_iw; K = D_MODEL; row = blk - M_TOK;
    } else {
        src = dw; q1 = dw1; q0 = dw0; sc = sc_dw; K = INNER; row = blk - M_TOK - 2 * INNER;
    }

    const float* r = src + (size_t)row * K;
    float mx = 0.f;
    for (int i = tid * 4; i < K; i += 1024) {
        const float4 v = *(const float4*)(r + i);
        mx = fmaxf(mx, fmaxf(fmaxf(fabsf(v.x), fabsf(v.y)),
                             fmaxf(fabsf(v.z), fabsf(v.w))));
    }
#pragma unroll
    for (int off = 1; off < 64; off <<= 1)
        mx = fmaxf(mx, __shfl_xor(mx, off, 64));
    __shared__ float red[4];
    if ((tid & 63) == 0) red[tid >> 6] = mx;
    __syncthreads();
    const float rm = fmaxf(fmaxf(red[0], red[1]), fmaxf(red[2], red[3]));
    const float q = rm > 0.f ? 127.f / rm : 0.f;

    for (int i = tid * 4; i < K; i += 1024) {
        const float4 v = *(const float4*)(r + i);
        float s1[4], s0[4];
        const float xv[4] = {v.x, v.y, v.z, v.w};
#pragma unroll
        for (int e = 0; e < 4; ++e) {
            const float t = xv[e] * q;
            s1[e] = rintf(t);
            s0[e] = rintf((t - s1[e]) * 254.f);
        }
        const size_t o = ((size_t)row * K + i) >> 2;
        ((int*)q1)[o] = pk8(s1[0], s1[1], s1[2], s1[3]);
        ((int*)q0)[o] = pk8(s0[0], s0[1], s0[2], s0[3]);
    }
    if (tid == 0) sc[row] = rm * (1.f / 127.f);
}

// ---------------------------------------------------------------------------
// int8 split MFMA GEMM: C[m,n] = scA[m]*scB[n] * (acc1 + acc2/254),
// acc1 = sum a1*b1, acc2 = sum (a1*b0 + a0*b1)  via mfma_i32_16x16x64_i8.
// Block tile (FRM*32) x (FRN*32), BK=64, 4 waves (2x2), dbuf counted-vmcnt,
// static-buffer unroll-by-2.  LDS row = 128B: granules 0..3 = a1, 4..7 = a0,
// XOR-swizzled by (row&7); staged via global_load_lds, pre-swizzled source.
// MODE 0: fp32 store.  MODE 1: softplus(v + b1[n] + b2[n]) stored as bf16.
// Requires nt = K/64 EVEN.
// ---------------------------------------------------------------------------
template <int MODE, int FRM, int FRN>
__global__ __launch_bounds__(256) void gemm_i8(
    const int8_t* __restrict__ A1g, const int8_t* __restrict__ A0g,
    const int8_t* __restrict__ B1g, const int8_t* __restrict__ B0g,
    const float* __restrict__ scA, const float* __restrict__ scB,
    void* __restrict__ Cv, const float* __restrict__ bias1,
    const float* __restrict__ bias2, int M, int N, int K)
{
    constexpr int BM = FRM * 32;
    constexpr int BN = FRN * 32;
    constexpr int SBUF = (BM + BN) * 128;
    __shared__ __align__(16) char smem[2 * SBUF];

    const int tid = threadIdx.x;
    const int w = tid >> 6;
    const int lane = tid & 63;

    const int gx = gridDim.x;
    const int nwg = gx * gridDim.y;
    int f = blockIdx.y * gx + blockIdx.x;
    f = (f & 7) * (nwg >> 3) + (f >> 3);
    const int bm = (f / gx) * BM;
    const int bn = (f % gx) * BN;

    const int wm = (w >> 1) * (FRM * 16);
    const int wn = (w & 1) * (FRN * 16);

    const int g8 = lane & 7;
    const int r8 = lane >> 3;
    const int srcg = g8 ^ r8;
    const int sbyte = (srcg & 3) * 16;
    const bool use_lo = (srcg & 4) != 0;

    const int8_t* pA[FRM];
    const int8_t* pB[FRN];
#pragma unroll
    for (int c = 0; c < FRM; ++c) {
        const int row = w * (FRM * 8) + c * 8 + r8;
        pA[c] = (use_lo ? A0g : A1g) + (size_t)(bm + row) * K + sbyte;
    }
#pragma unroll
    for (int c = 0; c < FRN; ++c) {
        const int row = w * (FRN * 8) + c * 8 + r8;
        pB[c] = (use_lo ? B0g : B1g) + (size_t)(bn + row) * K + sbyte;
    }

    i32x4 acc1[FRM][FRN] = {};
    i32x4 acc2[FRM][FRN] = {};
    const int fr = lane & 15;
    const int gk = lane >> 4;
    const int ghi = gk ^ (fr & 7);

    const int aoff1 = (wm + fr) * 128 + ghi * 16;
    const int aoff0 = (wm + fr) * 128 + (ghi ^ 4) * 16;
    const int boff1 = BM * 128 + (wn + fr) * 128 + ghi * 16;
    const int boff0 = BM * 128 + (wn + fr) * 128 + (ghi ^ 4) * 16;
    const char* const S0 = smem;
    const char* const S1 = smem + SBUF;

    const int nt = K >> 6;

#define STAGE_ALL(sb, kt)                                                           \
    {                                                                               \
        _Pragma("unroll")                                                           \
        for (int c = 0; c < FRM; ++c)                                               \
            __builtin_amdgcn_global_load_lds(                                       \
                (const __attribute__((address_space(1))) void*)(pA[c] + (kt)),      \
                (__attribute__((address_space(3))) void*)((char*)(sb) + (w * FRM + c) * 1024), \
                16, 0, 0);                                                          \
        _Pragma("unroll")                                                           \
        for (int c = 0; c < FRN; ++c)                                               \
            __builtin_amdgcn_global_load_lds(                                       \
                (const __attribute__((address_space(1))) void*)(pB[c] + (kt)),      \
                (__attribute__((address_space(3))) void*)((char*)(sb) + BM * 128 + (w * FRN + c) * 1024), \
                16, 0, 0);                                                          \
    }

#define WAIT_COUNTED()                                                              \
    if constexpr (FRM + FRN == 8) { asm volatile("s_waitcnt vmcnt(8)" ::: "memory"); } \
    else if constexpr (FRM + FRN == 6) { asm volatile("s_waitcnt vmcnt(6)" ::: "memory"); } \
    else { asm volatile("s_waitcnt vmcnt(4)" ::: "memory"); }

#define COMPUTE(S)                                                                  \
    {                                                                               \
        i32x4 a1[FRM], a0[FRM], b1[FRN], b0[FRN];                                   \
        _Pragma("unroll")                                                           \
        for (int i = 0; i < FRM; ++i) {                                             \
            a1[i] = *(const i32x4*)((S) + aoff1 + i * 2048);                        \
            a0[i] = *(const i32x4*)((S) + aoff0 + i * 2048);                        \
        }                                                                           \
        _Pragma("unroll")                                                           \
        for (int j = 0; j < FRN; ++j) {                                             \
            b1[j] = *(const i32x4*)((S) + boff1 + j * 2048);                        \
            b0[j] = *(const i32x4*)((S) + boff0 + j * 2048);                        \
        }                                                                           \
        _Pragma("unroll")                                                           \
        for (int i = 0; i < FRM; ++i)                                               \
            _Pragma("unroll")                                                       \
            for (int j = 0; j < FRN; ++j) {                                         \
                acc1[i][j] = __builtin_amdgcn_mfma_i32_16x16x64_i8(a1[i], b1[j], acc1[i][j], 0, 0, 0); \
                acc2[i][j] = __builtin_amdgcn_mfma_i32_16x16x64_i8(a1[i], b0[j], acc2[i][j], 0, 0, 0); \
                acc2[i][j] = __builtin_amdgcn_mfma_i32_16x16x64_i8(a0[i], b1[j], acc2[i][j], 0, 0, 0); \
            }                                                                       \
    }

    STAGE_ALL(S0, 0)

    for (int t = 0; t < nt; t += 2) {
        STAGE_ALL(S1, (t + 1) * 64)
        WAIT_COUNTED()
        __builtin_amdgcn_s_barrier();
        __builtin_amdgcn_sched_barrier(0);
        __builtin_amdgcn_s_setprio(1);
        COMPUTE(S0)
        __builtin_amdgcn_s_setprio(0);
        __builtin_amdgcn_sched_barrier(0);
        __builtin_amdgcn_s_barrier();

        const int k2 = (t + 2 < nt) ? (t + 2) * 64 : (nt - 1) * 64;
        STAGE_ALL(S0, k2)
        WAIT_COUNTED()
        __builtin_amdgcn_s_barrier();
        __builtin_amdgcn_sched_barrier(0);
        __builtin_amdgcn_s_setprio(1);
        COMPUTE(S1)
        __builtin_amdgcn_s_setprio(0);
        __builtin_amdgcn_sched_barrier(0);
        __builtin_amdgcn_s_barrier();
    }
#undef STAGE_ALL
#undef WAIT_COUNTED
#undef COMPUTE

    const int r0 = (lane >> 4) * 4;
#pragma unroll
    for (int i = 0; i < FRM; ++i) {
        const int row0 = bm + wm + i * 16 + r0;
        float sA[4];
#pragma unroll
        for (int r = 0; r < 4; ++r) sA[r] = scA[row0 + r];
#pragma unroll
        for (int j = 0; j < FRN; ++j) {
            const int col = bn + wn + j * 16 + fr;
            const float sB = scB[col];
            float add = 0.f;
            if constexpr (MODE == 1) add = bias1[col] + bias2[col];
#pragma unroll
            for (int r = 0; r < 4; ++r) {
                float v = ((float)acc1[i][j][r] +
                           (float)acc2[i][j][r] * INV254) * (sA[r] * sB);
                if constexpr (MODE == 1) {
                    const float xx = v + add;
                    v = (xx > 20.f) ? xx : log1pf(expf(xx));
                    ((u16*)Cv)[(size_t)(row0 + r) * N + col] = f2bf(v);
                } else {
                    ((float*)Cv)[(size_t)(row0 + r) * N + col] = v;
                }
            }
        }
    }
}

// ---------------------------------------------------------------------------
// Split-bf16 MFMA GEMM (out_proj).  Unchanged structure.
// ---------------------------------------------------------------------------
template <int MODE, int FRM, int FRN>
__global__ __launch_bounds__(256) void gemm_mfma(
    const u16* __restrict__ Ah_g, const u16* __restrict__ Al_g,
    const u16* __restrict__ Bh_g, const u16* __restrict__ Bl_g,
    float* __restrict__ C, const float* __restrict__ bias1,
    const float* __restrict__ bias2, int M, int N, int K)
{
    constexpr int BM = FRM * 32;
    constexpr int BN = FRN * 32;
    constexpr int SBUF = (BM + BN) * 128;
    __shared__ __align__(16) char smem[2 * SBUF];

    const int tid = threadIdx.x;
    const int w = tid >> 6;
    const int lane = tid & 63;

    const int gx = gridDim.x;
    const int nwg = gx * gridDim.y;
    int f = blockIdx.y * gx + blockIdx.x;
    f = (f & 7) * (nwg >> 3) + (f >> 3);
    const int bm = (f / gx) * BM;
    const int bn = (f % gx) * BN;

    const int wm = (w >> 1) * (FRM * 16);
    const int wn = (w & 1) * (FRN * 16);

    const int g8 = lane & 7;
    const int r8 = lane >> 3;
    const int srcg = g8 ^ r8;
    const int scol = (srcg & 3) * 8;
    const bool use_lo = (srcg & 4) != 0;

    const u16* pA[FRM];
    const u16* pB[FRN];
#pragma unroll
    for (int c = 0; c < FRM; ++c) {
        const int row = w * (FRM * 8) + c * 8 + r8;
        pA[c] = (use_lo ? Al_g : Ah_g) + (size_t)(bm + row) * K + scol;
    }
#pragma unroll
    for (int c = 0; c < FRN; ++c) {
        const int row = w * (FRN * 8) + c * 8 + r8;
        pB[c] = (use_lo ? Bl_g : Bh_g) + (size_t)(bn + row) * K + scol;
    }

    f32x4 acc[FRM][FRN] = {};
    const int fr = lane & 15;
    const int gk = lane >> 4;
    const int ghi = gk ^ (fr & 7);

    const int aoff_h = (wm + fr) * 128 + ghi * 16;
    const int aoff_l = (wm + fr) * 128 + (ghi ^ 4) * 16;
    const int boff_h = BM * 128 + (wn + fr) * 128 + ghi * 16;
    const int boff_l = BM * 128 + (wn + fr) * 128 + (ghi ^ 4) * 16;
    const char* const S0 = smem;
    const char* const S1 = smem + SBUF;

    const int nt = K >> 5;

#define STAGE_ALL(sb, kt)                                                           \
    {                                                                               \
        _Pragma("unroll")                                                           \
        for (int c = 0; c < FRM; ++c)                                               \
            __builtin_amdgcn_global_load_lds(                                       \
                (const __attribute__((address_space(1))) void*)(pA[c] + (kt)),      \
                (__attribute__((address_space(3))) void*)((char*)(sb) + (w * FRM + c) * 1024), \
                16, 0, 0);                                                          \
        _Pragma("unroll")                                                           \
        for (int c = 0; c < FRN; ++c)                                               \
            __builtin_amdgcn_global_load_lds(                                       \
                (const __attribute__((address_space(1))) void*)(pB[c] + (kt)),      \
                (__attribute__((address_space(3))) void*)((char*)(sb) + BM * 128 + (w * FRN + c) * 1024), \
                16, 0, 0);                                                          \
    }

#define WAIT_COUNTED()                                                              \
    if constexpr (FRM + FRN == 8) { asm volatile("s_waitcnt vmcnt(8)" ::: "memory"); } \
    else if constexpr (FRM + FRN == 6) { asm volatile("s_waitcnt vmcnt(6)" ::: "memory"); } \
    else { asm volatile("s_waitcnt vmcnt(4)" ::: "memory"); }

#define COMPUTE(S)                                                                  \
    {                                                                               \
        bf8 ah[FRM], al[FRM], bh[FRN], bl[FRN];                                     \
        _Pragma("unroll")                                                           \
        for (int i = 0; i < FRM; ++i) {                                             \
            ah[i] = *(const bf8*)((S) + aoff_h + i * 2048);                         \
            al[i] = *(const bf8*)((S) + aoff_l + i * 2048);                         \
        }                                                                           \
        _Pragma("unroll")                                                           \
        for (int j = 0; j < FRN; ++j) {                                             \
            bh[j] = *(const bf8*)((S) + boff_h + j * 2048);                         \
            bl[j] = *(const bf8*)((S) + boff_l + j * 2048);                         \
        }                                                                           \
        _Pragma("unroll")                                                           \
        for (int i = 0; i < FRM; ++i)                                               \
            _Pragma("unroll")                                                       \
            for (int j = 0; j < FRN; ++j) {                                         \
                acc[i][j] = __builtin_amdgcn_mfma_f32_16x16x32_bf16(ah[i], bh[j], acc[i][j], 0, 0, 0); \
                acc[i][j] = __builtin_amdgcn_mfma_f32_16x16x32_bf16(ah[i], bl[j], acc[i][j], 0, 0, 0); \
                acc[i][j] = __builtin_amdgcn_mfma_f32_16x16x32_bf16(al[i], bh[j], acc[i][j], 0, 0, 0); \
            }                                                                       \
    }

    STAGE_ALL(S0, 0)

    for (int t = 0; t < nt; t += 2) {
        STAGE_ALL(S1, (t + 1) * 32)
        WAIT_COUNTED()
        __builtin_amdgcn_s_barrier();
        __builtin_amdgcn_sched_barrier(0);
        __builtin_amdgcn_s_setprio(1);
        COMPUTE(S0)
        __builtin_amdgcn_s_setprio(0);
        __builtin_amdgcn_sched_barrier(0);
        __builtin_amdgcn_s_barrier();

        const int k2 = (t + 2 < nt) ? (t + 2) * 32 : (nt - 1) * 32;
        STAGE_ALL(S0, k2)
        WAIT_COUNTED()
        __builtin_amdgcn_s_barrier();
        __builtin_amdgcn_sched_barrier(0);
        __builtin_amdgcn_s_setprio(1);
        COMPUTE(S1)
        __builtin_amdgcn_s_setprio(0);
        __builtin_amdgcn_sched_barrier(0);
        __builtin_amdgcn_s_barrier();
    }
#undef STAGE_ALL
#undef WAIT_COUNTED
#undef COMPUTE

    const int r0 = (lane >> 4) * 4;
#pragma unroll
    for (int i = 0; i < FRM; ++i) {
        const int row0 = bm + wm + i * 16 + r0;
#pragma unroll
        for (int j = 0; j < FRN; ++j) {
            const int col = bn + wn + j * 16 + fr;
            float add = 0.f;
            if constexpr (MODE == 1) add = bias1[col] + bias2[col];
#pragma unroll
            for (int r = 0; r < 4; ++r) {
                float v = acc[i][j][r];
                if constexpr (MODE == 1) {
                    const float xx = v + add;
                    v = (xx > 20.f) ? xx : log1pf(expf(xx));
                }
                C[(size_t)(row0 + r) * N + col] = v;
            }
        }
    }
}

// ---------------------------------------------------------------------------
// Depthwise causal conv + bias + SiLU, fused per-token int8 row-quant of u.
// One block per token (384 threads x 4 channels = 1536).
// ---------------------------------------------------------------------------
__global__ __launch_bounds__(384) void conv_silu_quant(
    const float* __restrict__ xz, const float* __restrict__ cw,
    const float* __restrict__ cb, int8_t* __restrict__ u1,
    int8_t* __restrict__ u0, float* __restrict__ su)
{
    const int m = blockIdx.x;
    const int tid = threadIdx.x;
    const int c4 = tid * 4;
    const int b = m >> 11;
    const int l = m & (SEQLEN - 1);

    float wt[4][4];
#pragma unroll
    for (int i = 0; i < 4; ++i) {
        const float4 wv = *(const float4*)&cw[(c4 + i) * 4];
        wt[i][0] = wv.x; wt[i][1] = wv.y; wt[i][2] = wv.z; wt[i][3] = wv.w;
    }
    const float4 bias = *(const float4*)&cb[c4];
    float a[4] = {bias.x, bias.y, bias.z, bias.w};

#pragma unroll
    for (int j = 0; j < 4; ++j) {
        const int ll = l - 3 + j;
        if (ll >= 0) {
            const float4 x = *(const float4*)&xz[(size_t)(b * SEQLEN + ll) * (2 * INNER) + c4];
            a[0] = fmaf(x.x, wt[0][j], a[0]);
            a[1] = fmaf(x.y, wt[1][j], a[1]);
            a[2] = fmaf(x.z, wt[2][j], a[2]);
            a[3] = fmaf(x.w, wt[3][j], a[3]);
        }
    }
    float o[4];
#pragma unroll
    for (int i = 0; i < 4; ++i) o[i] = a[i] / (1.f + __expf(-a[i]));

    float mx = fmaxf(fmaxf(fabsf(o[0]), fabsf(o[1])),
                     fmaxf(fabsf(o[2]), fabsf(o[3])));
#pragma unroll
    for (int off = 1; off < 64; off <<= 1)
        mx = fmaxf(mx, __shfl_xor(mx, off, 64));
    __shared__ float red[6];
    if ((tid & 63) == 0) red[tid >> 6] = mx;
    __syncthreads();
    float rm = red[0];
#pragma unroll
    for (int i = 1; i < 6; ++i) rm = fmaxf(rm, red[i]);
    const float q = rm > 0.f ? 127.f / rm : 0.f;

    float s1[4], s0[4];
#pragma unroll
    for (int e = 0; e < 4; ++e) {
        const float t = o[e] * q;
        s1[e] = rintf(t);
        s0[e] = rintf((t - s1[e]) * 254.f);
    }
    const size_t vi = ((size_t)m * INNER + c4) >> 2;
    ((int*)u1)[vi] = pk8(s1[0], s1[1], s1[2], s1[3]);
    ((int*)u0)[vi] = pk8(s0[0], s0[1], s0[2], s0[3]);
    if (tid == 0) su[m] = rm * (1.f / 127.f);
}

// ---------------------------------------------------------------------------
// Scan pass 1: one lane per channel, 16 states in registers, no shuffles.
// dt read as bf16; u reconstructed from int8 two-level quant.
// ---------------------------------------------------------------------------
__global__ __launch_bounds__(256) void scan_pass1(
    const u16* __restrict__ dtb, const int8_t* __restrict__ u1,
    const int8_t* __restrict__ u0, const float* __restrict__ su,
    const float* __restrict__ A_log, const float* __restrict__ Bp,
    float* __restrict__ hend, float* __restrict__ Sdt)
{
    const int ch = blockIdx.x * 256 + threadIdx.x;
    const int c = blockIdx.y;
    const int b = (ch >= INNER) ? 1 : 0;
    const int d = ch - b * INNER;

    float A2[D_STATE], Bn[D_STATE];
#pragma unroll
    for (int n = 0; n < D_STATE; n += 4) {
        const float4 av = *(const float4*)&A_log[d * D_STATE + n];
        const float4 bv = *(const float4*)&Bp[d * D_STATE + n];
        A2[n+0] = -expf(av.x) * 1.44269504f; Bn[n+0] = bv.x;
        A2[n+1] = -expf(av.y) * 1.44269504f; Bn[n+1] = bv.y;
        A2[n+2] = -expf(av.z) * 1.44269504f; Bn[n+2] = bv.z;
        A2[n+3] = -expf(av.w) * 1.44269504f; Bn[n+3] = bv.w;
    }

    const size_t base = (size_t)(b * SEQLEN + c * CL) * INNER + d;
    const u16* dtp = dtb + base;
    const int8_t* u1p = u1 + base;
    const int8_t* u0p = u0 + base;
    const float* sup = su + (b * SEQLEN + c * CL);

    float h[D_STATE] = {};
    float S = 0.f;

    float dtv = bf2f(dtp[0]);
    float uv = fmaf((float)u0p[0], INV254, (float)u1p[0]) * sup[0];

    for (int l = 0; l < CL; ++l) {
        float dtn = 0.f, un = 0.f;
        if (l + 1 < CL) {
            dtn = bf2f(dtp[(size_t)(l + 1) * INNER]);
            un = fmaf((float)u0p[(size_t)(l + 1) * INNER], INV254,
                      (float)u1p[(size_t)(l + 1) * INNER]) * sup[l + 1];
        }
        const float dtu = dtv * uv;
        S += dtv;
#pragma unroll
        for (int n = 0; n < D_STATE; ++n) {
            const float dA = exp2f(dtv * A2[n]);
            h[n] = fmaf(dA, h[n], dtu * Bn[n]);
        }
        dtv = dtn; uv = un;
    }

#pragma unroll
    for (int n = 0; n < D_STATE; ++n)
        hend[((size_t)c * D_STATE + n) * NCH + ch] = h[n];
    Sdt[(size_t)c * NCH + ch] = S;
}

// ---------------------------------------------------------------------------
// Combine: per (n, ch), walk chunks; P_c = exp2(A2 * Sdt_c).
// ---------------------------------------------------------------------------
__global__ __launch_bounds__(256) void scan_combine(
    const float* __restrict__ hend, const float* __restrict__ Sdt,
    const float* __restrict__ A_log, float* __restrict__ h0all)
{
    const int idx = blockIdx.x * 256 + threadIdx.x;
    const int n = idx / NCH;
    const int ch = idx - n * NCH;
    const int b = (ch >= INNER) ? 1 : 0;
    const int d = ch - b * INNER;
    const float A2 = -expf(A_log[d * D_STATE + n]) * 1.44269504f;

    float h0 = 0.f;
    for (int c = 0; c < NCHUNK; ++c) {
        const size_t o = ((size_t)c * D_STATE + n) * NCH + ch;
        h0all[o] = h0;
        const float P = exp2f(A2 * Sdt[(size_t)c * NCH + ch]);
        h0 = fmaf(P, h0, hend[o]);
    }
}

// ---------------------------------------------------------------------------
// Scan pass 2: lane per channel; y=(h.C + D*u)*silu(z) -> yg hi/lo bf16.
// ---------------------------------------------------------------------------
__global__ __launch_bounds__(256) void scan_pass2(
    const u16* __restrict__ dtb, const int8_t* __restrict__ u1,
    const int8_t* __restrict__ u0, const float* __restrict__ su,
    const float* __restrict__ xz, const float* __restrict__ A_log,
    const float* __restrict__ Bp, const float* __restrict__ Cp,
    const float* __restrict__ Dp, const float* __restrict__ h0all,
    u16* __restrict__ ygh, u16* __restrict__ ygl)
{
    const int ch = blockIdx.x * 256 + threadIdx.x;
    const int c = blockIdx.y;
    const int b = (ch >= INNER) ? 1 : 0;
    const int d = ch - b * INNER;

    float A2[D_STATE], Bn[D_STATE], Cn[D_STATE];
#pragma unroll
    for (int n = 0; n < D_STATE; n += 4) {
        const float4 av = *(const float4*)&A_log[d * D_STATE + n];
        const float4 bv = *(const float4*)&Bp[d * D_STATE + n];
        const float4 cv = *(const float4*)&Cp[d * D_STATE + n];
        A2[n+0] = -expf(av.x) * 1.44269504f; Bn[n+0] = bv.x; Cn[n+0] = cv.x;
        A2[n+1] = -expf(av.y) * 1.44269504f; Bn[n+1] = bv.y; Cn[n+1] = cv.y;
        A2[n+2] = -expf(av.z) * 1.44269504f; Bn[n+2] = bv.z; Cn[n+2] = cv.z;
        A2[n+3] = -expf(av.w) * 1.44269504f; Bn[n+3] = bv.w; Cn[n+3] = cv.w;
    }
    const float Dd = Dp[d];

    float h[D_STATE];
#pragma unroll
    for (int n = 0; n < D_STATE; ++n)
        h[n] = h0all[((size_t)c * D_STATE + n) * NCH + ch];

    const size_t base = (size_t)(b * SEQLEN + c * CL) * INNER + d;
    const u16* dtp = dtb + base;
    const int8_t* u1p = u1 + base;
    const int8_t* u0p = u0 + base;
    const float* sup = su + (b * SEQLEN + c * CL);
    const float* zp = xz + (size_t)(b * SEQLEN + c * CL) * (2 * INNER) + INNER + d;
    u16* yhp = ygh + base;
    u16* ylp = ygl + base;

    float dtv = bf2f(dtp[0]);
    float uv = fmaf((float)u0p[0], INV254, (float)u1p[0]) * sup[0];
    float zv = zp[0];

    for (int l = 0; l < CL; ++l) {
        float dtn = 0.f, un = 0.f, zn = 0.f;
        if (l + 1 < CL) {
            dtn = bf2f(dtp[(size_t)(l + 1) * INNER]);
            un = fmaf((float)u0p[(size_t)(l + 1) * INNER], INV254,
                      (float)u1p[(size_t)(l + 1) * INNER]) * sup[l + 1];
            zn = zp[(size_t)(l + 1) * (2 * INNER)];
        }
        const float dtu = dtv * uv;
        float y = 0.f;
#pragma unroll
        for (int n = 0; n < D_STATE; ++n) {
            const float dA = exp2f(dtv * A2[n]);
            h[n] = fmaf(dA, h[n], dtu * Bn[n]);
            y = fmaf(h[n], Cn[n], y);
        }
        const float sig = 1.f / (1.f + __expf(-zv));
        const float val = (y + Dd * uv) * (zv * sig);
        const u16 hv = f2bf(val);
        yhp[(size_t)l * INNER] = hv;
        ylp[(size_t)l * INNER] = f2bf(val - bf2f(hv));
        dtv = dtn; uv = un; zv = zn;
    }
}

// ---------------------------------------------------------------------------
extern "C" void kernel_launch(void* const* d_in, const int* in_sizes, int n_in,
                              void* d_out, int out_size, void* d_ws, size_t ws_size,
                              hipStream_t stream)
{
    const float* hs      = (const float*)d_in[0];
    const float* in_w    = (const float*)d_in[1];
    const float* out_w   = (const float*)d_in[2];
    const float* dt_w    = (const float*)d_in[3];
    const float* dt_b    = (const float*)d_in[4];
    const float* conv_w  = (const float*)d_in[5];
    const float* conv_b  = (const float*)d_in[6];
    const float* A_log   = (const float*)d_in[7];
    const float* Bp      = (const float*)d_in[8];
    const float* Cp      = (const float*)d_in[9];
    const float* Dp      = (const float*)d_in[10];
    const float* dt_bias = (const float*)d_in[11];
    float* out = (float*)d_out;

    float* xz    = (float*)d_ws;                                   // [4096,3072] f32
    float* hend  = xz + (size_t)M_TOK * 2 * INNER;                 // [128,16,3072]
    float* Sdt   = hend + (size_t)NCHUNK * D_STATE * NCH;          // [128,3072]
    float* h0all = Sdt + (size_t)NCHUNK * NCH;                     // [128,16,3072]
    float* su_u  = h0all + (size_t)NCHUNK * D_STATE * NCH;         // [4096]
    float* sc_hs = su_u + M_TOK;                                   // [4096]
    float* sc_iw = sc_hs + M_TOK;                                  // [3072]
    float* sc_dw = sc_iw + 2 * INNER;                              // [1536]
    u16* dtb = (u16*)(sc_dw + INNER);                              // [4096,1536] bf16
    u16* ygh = dtb + (size_t)M_TOK * INNER;
    u16* ygl = ygh + (size_t)M_TOK * INNER;
    u16* owh = ygl + (size_t)M_TOK * INNER;
    u16* owl = owh + (size_t)D_MODEL * INNER;
    int8_t* hs1 = (int8_t*)(owl + (size_t)D_MODEL * INNER);
    int8_t* hs0 = hs1 + (size_t)M_TOK * D_MODEL;
    int8_t* iw1 = hs0 + (size_t)M_TOK * D_MODEL;
    int8_t* iw0 = iw1 + (size_t)2 * INNER * D_MODEL;
    int8_t* dw1 = iw0 + (size_t)2 * INNER * D_MODEL;
    int8_t* dw0 = dw1 + (size_t)INNER * INNER;
    int8_t* u1  = dw0 + (size_t)INNER * INNER;
    int8_t* u0  = u1 + (size_t)M_TOK * INNER;

    const dim3 blk(256);

    // fused preprocessing (3 rowquants + out_w hi/lo split), one launch
    {
        const int nq = M_TOK + 2 * INNER + INNER;          // 8704 rowquant blocks
        const int nc = (D_MODEL * INNER / 4 + 255) / 256;  // 1152 cvt blocks
        prep_all<<<dim3(nq + nc), blk, 0, stream>>>(
            hs, hs1, hs0, sc_hs, in_w, iw1, iw0, sc_iw,
            dt_w, dw1, dw0, sc_dw, out_w, owh, owl);
    }

    // 1) in_proj (i8): xz = hs @ in_w^T   (24x32 = 768 blocks)
    gemm_i8<0, 4, 4><<<dim3(2 * INNER / 128, M_TOK / 128), blk, 0, stream>>>(
        hs1, hs0, iw1, iw0, sc_hs, sc_iw, xz, nullptr, nullptr,
        M_TOK, 2 * INNER, D_MODEL);

    // 2) conv + SiLU + per-token i8 quant -> u1/u0/su
    conv_silu_quant<<<dim3(M_TOK), dim3(384), 0, stream>>>(
        xz, conv_w, conv_b, u1, u0, su_u);

    // 3) dt_proj (i8): dt = softplus(u @ dt_w^T + biases) -> bf16
    gemm_i8<1, 4, 2><<<dim3(INNER / 64, M_TOK / 128), blk, 0, stream>>>(
        u1, u0, dw1, dw0, su_u, sc_dw, dtb, dt_b, dt_bias,
        M_TOK, INNER, INNER);

    // 4) chunked selective scan (128 chunks of 16 steps)
    scan_pass1<<<dim3(NCH / 256, NCHUNK), blk, 0, stream>>>(
        dtb, u1, u0, su_u, A_log, Bp, hend, Sdt);
    scan_combine<<<dim3((D_STATE * NCH) / 256), blk, 0, stream>>>(
        hend, Sdt, A_log, h0all);
    scan_pass2<<<dim3(NCH / 256, NCHUNK), blk, 0, stream>>>(
        dtb, u1, u0, su_u, xz, A_log, Bp, Cp, Dp, h0all, ygh, ygl);

    // 5) out_proj (bf16 split): out = yg @ out_w^T   (12x64 = 768 blocks)
    gemm_mfma<0, 2, 2><<<dim3(D_MODEL / 64, M_TOK / 64), blk, 0, stream>>>(
        ygh, ygl, owh, owl, out, nullptr, nullptr, M_TOK, D_MODEL, INNER);
}

// Round 13
// 284.989 us; speedup vs baseline: 1.0738x; 1.0738x over previous
//
#include <hip/hip_runtime.h>
#include <cstdint>
#include <cstddef>

#define D_MODEL 768
#define D_STATE 16
#define D_CONV  4
#define INNER   1536
#define BATCH   2
#define SEQLEN  2048
#define M_TOK   (BATCH * SEQLEN)   // 4096
#define NCH     (BATCH * INNER)    // 3072
#define NCHUNK  128
#define CL      (SEQLEN / NCHUNK)  // 16

typedef unsigned short u16;
typedef __attribute__((ext_vector_type(4))) unsigned short us4;
typedef __attribute__((ext_vector_type(4))) float f32x4;
typedef __attribute__((ext_vector_type(4))) int i32x4;

#define INV254 (1.f / 254.f)

__device__ __forceinline__ u16 f2bf(float f) {
    uint32_t x = __float_as_uint(f);
    return (u16)((x + 0x7fffu + ((x >> 16) & 1u)) >> 16);
}
__device__ __forceinline__ float bf2f(u16 h) {
    return __uint_as_float(((uint32_t)h) << 16);
}
__device__ __forceinline__ int pk8(float a, float b, float c, float d) {
    return ((int)a & 0xff) | (((int)b & 0xff) << 8) |
           (((int)c & 0xff) << 16) | (((int)d & 0xff) << 24);
}

// ---------------------------------------------------------------------------
// Generic per-row int8 two-level quantization: s = rowmax/127,
// A ~= s*(a1 + a0/254).  One block per row, 256 threads, K % 4 == 0.
// ---------------------------------------------------------------------------
__device__ __forceinline__ void rowquant_body(
    const float* __restrict__ r, int8_t* __restrict__ q1,
    int8_t* __restrict__ q0, float* __restrict__ sc,
    int K, size_t rowbase, int tid)
{
    float mx = 0.f;
    for (int i = tid * 4; i < K; i += 1024) {
        const float4 v = *(const float4*)(r + i);
        mx = fmaxf(mx, fmaxf(fmaxf(fabsf(v.x), fabsf(v.y)),
                             fmaxf(fabsf(v.z), fabsf(v.w))));
    }
#pragma unroll
    for (int off = 1; off < 64; off <<= 1)
        mx = fmaxf(mx, __shfl_xor(mx, off, 64));
    __shared__ float red[4];
    if ((tid & 63) == 0) red[tid >> 6] = mx;
    __syncthreads();
    const float rm = fmaxf(fmaxf(red[0], red[1]), fmaxf(red[2], red[3]));
    const float q = rm > 0.f ? 127.f / rm : 0.f;

    for (int i = tid * 4; i < K; i += 1024) {
        const float4 v = *(const float4*)(r + i);
        float s1[4], s0[4];
        const float xv[4] = {v.x, v.y, v.z, v.w};
#pragma unroll
        for (int e = 0; e < 4; ++e) {
            const float t = xv[e] * q;
            s1[e] = rintf(t);
            s0[e] = rintf((t - s1[e]) * 254.f);
        }
        const size_t o = (rowbase + i) >> 2;
        ((int*)q1)[o] = pk8(s1[0], s1[1], s1[2], s1[3]);
        ((int*)q0)[o] = pk8(s0[0], s0[1], s0[2], s0[3]);
    }
    if (tid == 0) *sc = rm * (1.f / 127.f);
}

// Fused preprocessing: rowquant of hs, in_w, dt_w, out_w in one launch.
__global__ __launch_bounds__(256) void prep_all(
    const float* __restrict__ hs, int8_t* __restrict__ hs1, int8_t* __restrict__ hs0, float* __restrict__ sc_hs,
    const float* __restrict__ iw, int8_t* __restrict__ iw1, int8_t* __restrict__ iw0, float* __restrict__ sc_iw,
    const float* __restrict__ dw, int8_t* __restrict__ dw1, int8_t* __restrict__ dw0, float* __restrict__ sc_dw,
    const float* __restrict__ ow, int8_t* __restrict__ ow1, int8_t* __restrict__ ow0, float* __restrict__ sc_ow)
{
    const int blk = blockIdx.x;
    const int tid = threadIdx.x;
    const float* src; int8_t* q1; int8_t* q0; float* sc; int K; int row;
    if (blk < M_TOK) {
        src = hs; q1 = hs1; q0 = hs0; sc = sc_hs; K = D_MODEL; row = blk;
    } else if (blk < M_TOK + 2 * INNER) {
        src = iw; q1 = iw1; q0 = iw0; sc = sc_iw; K = D_MODEL; row = blk - M_TOK;
    } else if (blk < M_TOK + 3 * INNER) {
        src = dw; q1 = dw1; q0 = dw0; sc = sc_dw; K = INNER; row = blk - M_TOK - 2 * INNER;
    } else {
        src = ow; q1 = ow1; q0 = ow0; sc = sc_ow; K = INNER; row = blk - M_TOK - 3 * INNER;
    }
    rowquant_body(src + (size_t)row * K, q1, q0, sc + row, K,
                  (size_t)row * K, tid);
}

// Standalone rowquant for yg (runs after scan_pass2).
__global__ __launch_bounds__(256) void rowquant_yg(
    const float* __restrict__ src, int8_t* __restrict__ q1,
    int8_t* __restrict__ q0, float* __restrict__ sc)
{
    const int row = blockIdx.x;
    rowquant_body(src + (size_t)row * INNER, q1, q0, sc + row, INNER,
                  (size_t)row * INNER, threadIdx.x);
}

// ---------------------------------------------------------------------------
// int8 split MFMA GEMM: C[m,n] = scA[m]*scB[n] * (acc1 + acc2/254),
// acc1 = sum a1*b1, acc2 = sum (a1*b0 + a0*b1)  via mfma_i32_16x16x64_i8.
// Block tile (FRM*32) x (FRN*32), BK=64, 4 waves (2x2), dbuf counted-vmcnt,
// static-buffer unroll-by-2.  LDS row = 128B: granules 0..3 = a1, 4..7 = a0,
// XOR-swizzled by (row&7); staged via global_load_lds, pre-swizzled source.
// MODE 0: fp32 store.  MODE 1: softplus(v + b1[n] + b2[n]) stored as bf16.
// Requires nt = K/64 EVEN.
// ---------------------------------------------------------------------------
template <int MODE, int FRM, int FRN>
__global__ __launch_bounds__(256) void gemm_i8(
    const int8_t* __restrict__ A1g, const int8_t* __restrict__ A0g,
    const int8_t* __restrict__ B1g, const int8_t* __restrict__ B0g,
    const float* __restrict__ scA, const float* __restrict__ scB,
    void* __restrict__ Cv, const float* __restrict__ bias1,
    const float* __restrict__ bias2, int M, int N, int K)
{
    constexpr int BM = FRM * 32;
    constexpr int BN = FRN * 32;
    constexpr int SBUF = (BM + BN) * 128;
    __shared__ __align__(16) char smem[2 * SBUF];

    const int tid = threadIdx.x;
    const int w = tid >> 6;
    const int lane = tid & 63;

    const int gx = gridDim.x;
    const int nwg = gx * gridDim.y;
    int f = blockIdx.y * gx + blockIdx.x;
    f = (f & 7) * (nwg >> 3) + (f >> 3);
    const int bm = (f / gx) * BM;
    const int bn = (f % gx) * BN;

    const int wm = (w >> 1) * (FRM * 16);
    const int wn = (w & 1) * (FRN * 16);

    const int g8 = lane & 7;
    const int r8 = lane >> 3;
    const int srcg = g8 ^ r8;
    const int sbyte = (srcg & 3) * 16;
    const bool use_lo = (srcg & 4) != 0;

    const int8_t* pA[FRM];
    const int8_t* pB[FRN];
#pragma unroll
    for (int c = 0; c < FRM; ++c) {
        const int row = w * (FRM * 8) + c * 8 + r8;
        pA[c] = (use_lo ? A0g : A1g) + (size_t)(bm + row) * K + sbyte;
    }
#pragma unroll
    for (int c = 0; c < FRN; ++c) {
        const int row = w * (FRN * 8) + c * 8 + r8;
        pB[c] = (use_lo ? B0g : B1g) + (size_t)(bn + row) * K + sbyte;
    }

    i32x4 acc1[FRM][FRN] = {};
    i32x4 acc2[FRM][FRN] = {};
    const int fr = lane & 15;
    const int gk = lane >> 4;
    const int ghi = gk ^ (fr & 7);

    const int aoff1 = (wm + fr) * 128 + ghi * 16;
    const int aoff0 = (wm + fr) * 128 + (ghi ^ 4) * 16;
    const int boff1 = BM * 128 + (wn + fr) * 128 + ghi * 16;
    const int boff0 = BM * 128 + (wn + fr) * 128 + (ghi ^ 4) * 16;
    const char* const S0 = smem;
    const char* const S1 = smem + SBUF;

    const int nt = K >> 6;

#define STAGE_ALL(sb, kt)                                                           \
    {                                                                               \
        _Pragma("unroll")                                                           \
        for (int c = 0; c < FRM; ++c)                                               \
            __builtin_amdgcn_global_load_lds(                                       \
                (const __attribute__((address_space(1))) void*)(pA[c] + (kt)),      \
                (__attribute__((address_space(3))) void*)((char*)(sb) + (w * FRM + c) * 1024), \
                16, 0, 0);                                                          \
        _Pragma("unroll")                                                           \
        for (int c = 0; c < FRN; ++c)                                               \
            __builtin_amdgcn_global_load_lds(                                       \
                (const __attribute__((address_space(1))) void*)(pB[c] + (kt)),      \
                (__attribute__((address_space(3))) void*)((char*)(sb) + BM * 128 + (w * FRN + c) * 1024), \
                16, 0, 0);                                                          \
    }

#define WAIT_COUNTED()                                                              \
    if constexpr (FRM + FRN == 8) { asm volatile("s_waitcnt vmcnt(8)" ::: "memory"); } \
    else if constexpr (FRM + FRN == 6) { asm volatile("s_waitcnt vmcnt(6)" ::: "memory"); } \
    else { asm volatile("s_waitcnt vmcnt(4)" ::: "memory"); }

#define COMPUTE(S)                                                                  \
    {                                                                               \
        i32x4 a1[FRM], a0[FRM], b1[FRN], b0[FRN];                                   \
        _Pragma("unroll")                                                           \
        for (int i = 0; i < FRM; ++i) {                                             \
            a1[i] = *(const i32x4*)((S) + aoff1 + i * 2048);                        \
            a0[i] = *(const i32x4*)((S) + aoff0 + i * 2048);                        \
        }                                                                           \
        _Pragma("unroll")                                                           \
        for (int j = 0; j < FRN; ++j) {                                             \
            b1[j] = *(const i32x4*)((S) + boff1 + j * 2048);                        \
            b0[j] = *(const i32x4*)((S) + boff0 + j * 2048);                        \
        }                                                                           \
        _Pragma("unroll")                                                           \
        for (int i = 0; i < FRM; ++i)                                               \
            _Pragma("unroll")                                                       \
            for (int j = 0; j < FRN; ++j) {                                         \
                acc1[i][j] = __builtin_amdgcn_mfma_i32_16x16x64_i8(a1[i], b1[j], acc1[i][j], 0, 0, 0); \
                acc2[i][j] = __builtin_amdgcn_mfma_i32_16x16x64_i8(a1[i], b0[j], acc2[i][j], 0, 0, 0); \
                acc2[i][j] = __builtin_amdgcn_mfma_i32_16x16x64_i8(a0[i], b1[j], acc2[i][j], 0, 0, 0); \
            }                                                                       \
    }

    STAGE_ALL(S0, 0)

    for (int t = 0; t < nt; t += 2) {
        STAGE_ALL(S1, (t + 1) * 64)
        WAIT_COUNTED()
        __builtin_amdgcn_s_barrier();
        __builtin_amdgcn_sched_barrier(0);
        __builtin_amdgcn_s_setprio(1);
        COMPUTE(S0)
        __builtin_amdgcn_s_setprio(0);
        __builtin_amdgcn_sched_barrier(0);
        __builtin_amdgcn_s_barrier();

        const int k2 = (t + 2 < nt) ? (t + 2) * 64 : (nt - 1) * 64;
        STAGE_ALL(S0, k2)
        WAIT_COUNTED()
        __builtin_amdgcn_s_barrier();
        __builtin_amdgcn_sched_barrier(0);
        __builtin_amdgcn_s_setprio(1);
        COMPUTE(S1)
        __builtin_amdgcn_s_setprio(0);
        __builtin_amdgcn_sched_barrier(0);
        __builtin_amdgcn_s_barrier();
    }
#undef STAGE_ALL
#undef WAIT_COUNTED
#undef COMPUTE

    const int r0 = (lane >> 4) * 4;
#pragma unroll
    for (int i = 0; i < FRM; ++i) {
        const int row0 = bm + wm + i * 16 + r0;
        float sA[4];
#pragma unroll
        for (int r = 0; r < 4; ++r) sA[r] = scA[row0 + r];
#pragma unroll
        for (int j = 0; j < FRN; ++j) {
            const int col = bn + wn + j * 16 + fr;
            const float sB = scB[col];
            float add = 0.f;
            if constexpr (MODE == 1) add = bias1[col] + bias2[col];
#pragma unroll
            for (int r = 0; r < 4; ++r) {
                float v = ((float)acc1[i][j][r] +
                           (float)acc2[i][j][r] * INV254) * (sA[r] * sB);
                if constexpr (MODE == 1) {
                    const float xx = v + add;
                    v = (xx > 20.f) ? xx : log1pf(expf(xx));
                    ((u16*)Cv)[(size_t)(row0 + r) * N + col] = f2bf(v);
                } else {
                    ((float*)Cv)[(size_t)(row0 + r) * N + col] = v;
                }
            }
        }
    }
}

// ---------------------------------------------------------------------------
// Depthwise causal conv + bias + SiLU, fused per-token int8 row-quant of u.
// One block per token (384 threads x 4 channels = 1536).
// ---------------------------------------------------------------------------
__global__ __launch_bounds__(384) void conv_silu_quant(
    const float* __restrict__ xz, const float* __restrict__ cw,
    const float* __restrict__ cb, int8_t* __restrict__ u1,
    int8_t* __restrict__ u0, float* __restrict__ su)
{
    const int m = blockIdx.x;
    const int tid = threadIdx.x;
    const int c4 = tid * 4;
    const int b = m >> 11;
    const int l = m & (SEQLEN - 1);

    float wt[4][4];
#pragma unroll
    for (int i = 0; i < 4; ++i) {
        const float4 wv = *(const float4*)&cw[(c4 + i) * 4];
        wt[i][0] = wv.x; wt[i][1] = wv.y; wt[i][2] = wv.z; wt[i][3] = wv.w;
    }
    const float4 bias = *(const float4*)&cb[c4];
    float a[4] = {bias.x, bias.y, bias.z, bias.w};

#pragma unroll
    for (int j = 0; j < 4; ++j) {
        const int ll = l - 3 + j;
        if (ll >= 0) {
            const float4 x = *(const float4*)&xz[(size_t)(b * SEQLEN + ll) * (2 * INNER) + c4];
            a[0] = fmaf(x.x, wt[0][j], a[0]);
            a[1] = fmaf(x.y, wt[1][j], a[1]);
            a[2] = fmaf(x.z, wt[2][j], a[2]);
            a[3] = fmaf(x.w, wt[3][j], a[3]);
        }
    }
    float o[4];
#pragma unroll
    for (int i = 0; i < 4; ++i) o[i] = a[i] / (1.f + __expf(-a[i]));

    float mx = fmaxf(fmaxf(fabsf(o[0]), fabsf(o[1])),
                     fmaxf(fabsf(o[2]), fabsf(o[3])));
#pragma unroll
    for (int off = 1; off < 64; off <<= 1)
        mx = fmaxf(mx, __shfl_xor(mx, off, 64));
    __shared__ float red[6];
    if ((tid & 63) == 0) red[tid >> 6] = mx;
    __syncthreads();
    float rm = red[0];
#pragma unroll
    for (int i = 1; i < 6; ++i) rm = fmaxf(rm, red[i]);
    const float q = rm > 0.f ? 127.f / rm : 0.f;

    float s1[4], s0[4];
#pragma unroll
    for (int e = 0; e < 4; ++e) {
        const float t = o[e] * q;
        s1[e] = rintf(t);
        s0[e] = rintf((t - s1[e]) * 254.f);
    }
    const size_t vi = ((size_t)m * INNER + c4) >> 2;
    ((int*)u1)[vi] = pk8(s1[0], s1[1], s1[2], s1[3]);
    ((int*)u0)[vi] = pk8(s0[0], s0[1], s0[2], s0[3]);
    if (tid == 0) su[m] = rm * (1.f / 127.f);
}

// ---------------------------------------------------------------------------
// Scan pass 1: one lane per channel, 16 states in registers, no shuffles.
// ---------------------------------------------------------------------------
__global__ __launch_bounds__(256) void scan_pass1(
    const u16* __restrict__ dtb, const int8_t* __restrict__ u1,
    const int8_t* __restrict__ u0, const float* __restrict__ su,
    const float* __restrict__ A_log, const float* __restrict__ Bp,
    float* __restrict__ hend, float* __restrict__ Sdt)
{
    const int ch = blockIdx.x * 256 + threadIdx.x;
    const int c = blockIdx.y;
    const int b = (ch >= INNER) ? 1 : 0;
    const int d = ch - b * INNER;

    float A2[D_STATE], Bn[D_STATE];
#pragma unroll
    for (int n = 0; n < D_STATE; n += 4) {
        const float4 av = *(const float4*)&A_log[d * D_STATE + n];
        const float4 bv = *(const float4*)&Bp[d * D_STATE + n];
        A2[n+0] = -expf(av.x) * 1.44269504f; Bn[n+0] = bv.x;
        A2[n+1] = -expf(av.y) * 1.44269504f; Bn[n+1] = bv.y;
        A2[n+2] = -expf(av.z) * 1.44269504f; Bn[n+2] = bv.z;
        A2[n+3] = -expf(av.w) * 1.44269504f; Bn[n+3] = bv.w;
    }

    const size_t base = (size_t)(b * SEQLEN + c * CL) * INNER + d;
    const u16* dtp = dtb + base;
    const int8_t* u1p = u1 + base;
    const int8_t* u0p = u0 + base;
    const float* sup = su + (b * SEQLEN + c * CL);

    float h[D_STATE] = {};
    float S = 0.f;

    float dtv = bf2f(dtp[0]);
    float uv = fmaf((float)u0p[0], INV254, (float)u1p[0]) * sup[0];

    for (int l = 0; l < CL; ++l) {
        float dtn = 0.f, un = 0.f;
        if (l + 1 < CL) {
            dtn = bf2f(dtp[(size_t)(l + 1) * INNER]);
            un = fmaf((float)u0p[(size_t)(l + 1) * INNER], INV254,
                      (float)u1p[(size_t)(l + 1) * INNER]) * sup[l + 1];
        }
        const float dtu = dtv * uv;
        S += dtv;
#pragma unroll
        for (int n = 0; n < D_STATE; ++n) {
            const float dA = exp2f(dtv * A2[n]);
            h[n] = fmaf(dA, h[n], dtu * Bn[n]);
        }
        dtv = dtn; uv = un;
    }

#pragma unroll
    for (int n = 0; n < D_STATE; ++n)
        hend[((size_t)c * D_STATE + n) * NCH + ch] = h[n];
    Sdt[(size_t)c * NCH + ch] = S;
}

// ---------------------------------------------------------------------------
// Combine: per (n, ch), walk chunks; P_c = exp2(A2 * Sdt_c).
// ---------------------------------------------------------------------------
__global__ __launch_bounds__(256) void scan_combine(
    const float* __restrict__ hend, const float* __restrict__ Sdt,
    const float* __restrict__ A_log, float* __restrict__ h0all)
{
    const int idx = blockIdx.x * 256 + threadIdx.x;
    const int n = idx / NCH;
    const int ch = idx - n * NCH;
    const int b = (ch >= INNER) ? 1 : 0;
    const int d = ch - b * INNER;
    const float A2 = -expf(A_log[d * D_STATE + n]) * 1.44269504f;

    float h0 = 0.f;
    for (int c = 0; c < NCHUNK; ++c) {
        const size_t o = ((size_t)c * D_STATE + n) * NCH + ch;
        h0all[o] = h0;
        const float P = exp2f(A2 * Sdt[(size_t)c * NCH + ch]);
        h0 = fmaf(P, h0, hend[o]);
    }
}

// ---------------------------------------------------------------------------
// Scan pass 2: lane per channel; y=(h.C + D*u)*silu(z) -> yg f32.
// ---------------------------------------------------------------------------
__global__ __launch_bounds__(256) void scan_pass2(
    const u16* __restrict__ dtb, const int8_t* __restrict__ u1,
    const int8_t* __restrict__ u0, const float* __restrict__ su,
    const float* __restrict__ xz, const float* __restrict__ A_log,
    const float* __restrict__ Bp, const float* __restrict__ Cp,
    const float* __restrict__ Dp, const float* __restrict__ h0all,
    float* __restrict__ yg)
{
    const int ch = blockIdx.x * 256 + threadIdx.x;
    const int c = blockIdx.y;
    const int b = (ch >= INNER) ? 1 : 0;
    const int d = ch - b * INNER;

    float A2[D_STATE], Bn[D_STATE], Cn[D_STATE];
#pragma unroll
    for (int n = 0; n < D_STATE; n += 4) {
        const float4 av = *(const float4*)&A_log[d * D_STATE + n];
        const float4 bv = *(const float4*)&Bp[d * D_STATE + n];
        const float4 cv = *(const float4*)&Cp[d * D_STATE + n];
        A2[n+0] = -expf(av.x) * 1.44269504f; Bn[n+0] = bv.x; Cn[n+0] = cv.x;
        A2[n+1] = -expf(av.y) * 1.44269504f; Bn[n+1] = bv.y; Cn[n+1] = cv.y;
        A2[n+2] = -expf(av.z) * 1.44269504f; Bn[n+2] = bv.z; Cn[n+2] = cv.z;
        A2[n+3] = -expf(av.w) * 1.44269504f; Bn[n+3] = bv.w; Cn[n+3] = cv.w;
    }
    const float Dd = Dp[d];

    float h[D_STATE];
#pragma unroll
    for (int n = 0; n < D_STATE; ++n)
        h[n] = h0all[((size_t)c * D_STATE + n) * NCH + ch];

    const size_t base = (size_t)(b * SEQLEN + c * CL) * INNER + d;
    const u16* dtp = dtb + base;
    const int8_t* u1p = u1 + base;
    const int8_t* u0p = u0 + base;
    const float* sup = su + (b * SEQLEN + c * CL);
    const float* zp = xz + (size_t)(b * SEQLEN + c * CL) * (2 * INNER) + INNER + d;
    float* ygp = yg + base;

    float dtv = bf2f(dtp[0]);
    float uv = fmaf((float)u0p[0], INV254, (float)u1p[0]) * sup[0];
    float zv = zp[0];

    for (int l = 0; l < CL; ++l) {
        float dtn = 0.f, un = 0.f, zn = 0.f;
        if (l + 1 < CL) {
            dtn = bf2f(dtp[(size_t)(l + 1) * INNER]);
            un = fmaf((float)u0p[(size_t)(l + 1) * INNER], INV254,
                      (float)u1p[(size_t)(l + 1) * INNER]) * sup[l + 1];
            zn = zp[(size_t)(l + 1) * (2 * INNER)];
        }
        const float dtu = dtv * uv;
        float y = 0.f;
#pragma unroll
        for (int n = 0; n < D_STATE; ++n) {
            const float dA = exp2f(dtv * A2[n]);
            h[n] = fmaf(dA, h[n], dtu * Bn[n]);
            y = fmaf(h[n], Cn[n], y);
        }
        const float sig = 1.f / (1.f + __expf(-zv));
        ygp[(size_t)l * INNER] = (y + Dd * uv) * (zv * sig);
        dtv = dtn; uv = un; zv = zn;
    }
}

// ---------------------------------------------------------------------------
extern "C" void kernel_launch(void* const* d_in, const int* in_sizes, int n_in,
                              void* d_out, int out_size, void* d_ws, size_t ws_size,
                              hipStream_t stream)
{
    const float* hs      = (const float*)d_in[0];
    const float* in_w    = (const float*)d_in[1];
    const float* out_w   = (const float*)d_in[2];
    const float* dt_w    = (const float*)d_in[3];
    const float* dt_b    = (const float*)d_in[4];
    const float* conv_w  = (const float*)d_in[5];
    const float* conv_b  = (const float*)d_in[6];
    const float* A_log   = (const float*)d_in[7];
    const float* Bp      = (const float*)d_in[8];
    const float* Cp      = (const float*)d_in[9];
    const float* Dp      = (const float*)d_in[10];
    const float* dt_bias = (const float*)d_in[11];
    float* out = (float*)d_out;

    float* xz    = (float*)d_ws;                                   // [4096,3072] f32
    float* hend  = xz + (size_t)M_TOK * 2 * INNER;                 // [128,16,3072]
    float* Sdt   = hend + (size_t)NCHUNK * D_STATE * NCH;          // [128,3072]
    float* h0all = Sdt + (size_t)NCHUNK * NCH;                     // [128,16,3072]
    float* yg    = h0all + (size_t)NCHUNK * D_STATE * NCH;         // [4096,1536] f32
    float* su_u  = yg + (size_t)M_TOK * INNER;                     // [4096]
    float* sc_hs = su_u + M_TOK;                                   // [4096]
    float* sc_iw = sc_hs + M_TOK;                                  // [3072]
    float* sc_dw = sc_iw + 2 * INNER;                              // [1536]
    float* sc_ow = sc_dw + INNER;                                  // [768]
    float* sc_yg = sc_ow + D_MODEL;                                // [4096]
    u16* dtb = (u16*)(sc_yg + M_TOK);                              // [4096,1536] bf16
    int8_t* hs1 = (int8_t*)(dtb + (size_t)M_TOK * INNER);
    int8_t* hs0 = hs1 + (size_t)M_TOK * D_MODEL;
    int8_t* iw1 = hs0 + (size_t)M_TOK * D_MODEL;
    int8_t* iw0 = iw1 + (size_t)2 * INNER * D_MODEL;
    int8_t* dw1 = iw0 + (size_t)2 * INNER * D_MODEL;
    int8_t* dw0 = dw1 + (size_t)INNER * INNER;
    int8_t* ow1 = dw0 + (size_t)INNER * INNER;
    int8_t* ow0 = ow1 + (size_t)D_MODEL * INNER;
    int8_t* u1  = ow0 + (size_t)D_MODEL * INNER;
    int8_t* u0  = u1 + (size_t)M_TOK * INNER;
    int8_t* yg1 = u0 + (size_t)M_TOK * INNER;
    int8_t* yg0 = yg1 + (size_t)M_TOK * INNER;

    const dim3 blk(256);

    // fused preprocessing: rowquant of hs, in_w, dt_w, out_w (one launch)
    prep_all<<<dim3(M_TOK + 3 * INNER + D_MODEL), blk, 0, stream>>>(
        hs, hs1, hs0, sc_hs, in_w, iw1, iw0, sc_iw,
        dt_w, dw1, dw0, sc_dw, out_w, ow1, ow0, sc_ow);

    // 1) in_proj (i8, 128x64 tiles): xz = hs @ in_w^T  (48x32 = 1536 blocks)
    gemm_i8<0, 4, 2><<<dim3(2 * INNER / 64, M_TOK / 128), blk, 0, stream>>>(
        hs1, hs0, iw1, iw0, sc_hs, sc_iw, xz, nullptr, nullptr,
        M_TOK, 2 * INNER, D_MODEL);

    // 2) conv + SiLU + per-token i8 quant -> u1/u0/su
    conv_silu_quant<<<dim3(M_TOK), dim3(384), 0, stream>>>(
        xz, conv_w, conv_b, u1, u0, su_u);

    // 3) dt_proj (i8): dt = softplus(u @ dt_w^T + biases) -> bf16
    gemm_i8<1, 4, 2><<<dim3(INNER / 64, M_TOK / 128), blk, 0, stream>>>(
        u1, u0, dw1, dw0, su_u, sc_dw, dtb, dt_b, dt_bias,
        M_TOK, INNER, INNER);

    // 4) chunked selective scan (128 chunks of 16 steps) -> yg f32
    scan_pass1<<<dim3(NCH / 256, NCHUNK), blk, 0, stream>>>(
        dtb, u1, u0, su_u, A_log, Bp, hend, Sdt);
    scan_combine<<<dim3((D_STATE * NCH) / 256), blk, 0, stream>>>(
        hend, Sdt, A_log, h0all);
    scan_pass2<<<dim3(NCH / 256, NCHUNK), blk, 0, stream>>>(
        dtb, u1, u0, su_u, xz, A_log, Bp, Cp, Dp, h0all, yg);

    // 4b) per-token i8 quant of yg
    rowquant_yg<<<dim3(M_TOK), blk, 0, stream>>>(yg, yg1, yg0, sc_yg);

    // 5) out_proj (i8): out = yg @ out_w^T   (12x64 = 768 blocks)
    gemm_i8<0, 2, 2><<<dim3(D_MODEL / 64, M_TOK / 64), blk, 0, stream>>>(
        yg1, yg0, ow1, ow0, sc_yg, sc_ow, out, nullptr, nullptr,
        M_TOK, D_MODEL, INNER);
}